// Round 12
// baseline (185.723 us; speedup 1.0000x reference)
//
#include <hip/hip_runtime.h>
#include <cstdint>
#include <cstddef>

// Problem constants
#define B_   2
#define S_   2048
#define D_   1024
#define H_   16
#define DH_  64
#define NROW (B_ * S_)   // 4096 rows for all projection GEMMs

typedef __bf16  bf16x8 __attribute__((ext_vector_type(8)));
typedef __bf16  bf16x4 __attribute__((ext_vector_type(4)));
typedef float   f32x4  __attribute__((ext_vector_type(4)));

#define MFMA16(a, b, c) __builtin_amdgcn_mfma_f32_16x16x32_bf16((a), (b), (c), 0, 0, 0)

__device__ __forceinline__ void gload_lds16(const void* g, void* l) {
  __builtin_amdgcn_global_load_lds(
      (__attribute__((address_space(1))) void*)(g),
      (__attribute__((address_space(3))) void*)(l), 16, 0, 0);
}

// ---------------------------------------------------------------------------
// single fused cast: 3 X inputs (4096 blocks each) + 4 W inputs (1024 each)
struct CastArgs { const float* src[7]; __bf16* dst[7]; };

__global__ void cast_all(CastArgs a) {
  int b = blockIdx.x, which, idx;
  if (b < 12288) { which = b >> 12; idx = b & 4095; }
  else { b -= 12288; which = 3 + (b >> 10); idx = b & 1023; }
  const int i = idx * 256 + threadIdx.x;
  const float4 v = ((const float4*)a.src[which])[i];
  bf16x4 o;
  o[0] = (__bf16)v.x; o[1] = (__bf16)v.y; o[2] = (__bf16)v.z; o[3] = (__bf16)v.w;
  ((bf16x4*)a.dst[which])[i] = o;
}

// ---------------------------------------------------------------------------
// Fused QKV projection, BK=64 + XOR swizzle (unchanged from R9).
// NOTE: BK=128 here would need 64 KB LDS -> 2 blocks/CU (m132 cliff); stays 64.
struct QKVArgs {
  const __bf16* A[3]; const __bf16* W[3]; const float* bias[3]; __bf16* C[3];
};

__global__ __launch_bounds__(256, 3) void gemm_qkv(QKVArgs args) {
  __shared__ __bf16 As[128 * 64];   // 16 KB
  __shared__ __bf16 Bs[128 * 64];   // 16 KB
  const int z = blockIdx.z;
  const __bf16* A = args.A[z];
  const __bf16* W = args.W[z];
  const float* bias = args.bias[z];
  __bf16* C = args.C[z];
  const int tid  = threadIdx.x;
  const int lane = tid & 63, wave = tid >> 6;
  const int lo   = lane & 15, quad = lane >> 4;
  const int wr   = wave & 1,  wc   = wave >> 1;
  const int bn   = blockIdx.x, bm = blockIdx.y;
  const __bf16* Ag = A + (size_t)bn * 128 * D_;
  const __bf16* Wg = W + (size_t)bm * 128 * D_;
  int srow[4], soff[4];
#pragma unroll
  for (int u = 0; u < 4; u++) {
    const int c = tid + u * 256;
    srow[u] = c >> 3;
    soff[u] = (((c & 7) ^ ((c >> 3) & 7)) * 8);
  }

  f32x4 acc[4][4] = {};
  for (int k0 = 0; k0 < D_; k0 += 64) {
    __syncthreads();
#pragma unroll
    for (int u = 0; u < 4; u++) {
      gload_lds16(Ag + (size_t)srow[u] * D_ + k0 + soff[u], &As[(tid + u * 256) * 8]);
      gload_lds16(Wg + (size_t)srow[u] * D_ + k0 + soff[u], &Bs[(tid + u * 256) * 8]);
    }
    __syncthreads();
#pragma unroll
    for (int h = 0; h < 2; h++) {
      bf16x8 af[4], bfr[4];
#pragma unroll
      for (int i = 0; i < 4; i++) {
        const int r = wr * 64 + i * 16 + lo;
        af[i] = *(const bf16x8*)&As[r * 64 + (((h * 4 + quad) ^ (r & 7)) * 8)];
      }
#pragma unroll
      for (int j = 0; j < 4; j++) {
        const int r = wc * 64 + j * 16 + lo;
        bfr[j] = *(const bf16x8*)&Bs[r * 64 + (((h * 4 + quad) ^ (r & 7)) * 8)];
      }
#pragma unroll
      for (int i = 0; i < 4; i++)
#pragma unroll
        for (int j = 0; j < 4; j++)
          acc[i][j] = MFMA16(af[i], bfr[j], acc[i][j]);
    }
  }
  if (z == 2) {
#pragma unroll
    for (int i = 0; i < 4; i++) {
      const int row0 = bn * 128 + wr * 64 + i * 16 + quad * 4;
      const int bb = row0 >> 11, s = row0 & (S_ - 1);
#pragma unroll
      for (int j = 0; j < 4; j++) {
        const int col = bm * 128 + wc * 64 + j * 16 + lo;
        const int hh = col >> 6, dd = col & 63;
        const float bv = bias[col];
        bf16x4 o;
#pragma unroll
        for (int r = 0; r < 4; r++) o[r] = (__bf16)(acc[i][j][r] + bv);
        *(bf16x4*)&C[((size_t)(bb * H_ + hh) * DH_ + dd) * S_ + s] = o;
      }
    }
  } else {
#pragma unroll
    for (int i = 0; i < 4; i++) {
      const int row = bn * 128 + wr * 64 + i * 16 + quad * 4;
#pragma unroll
      for (int j = 0; j < 4; j++) {
        const int col = bm * 128 + wc * 64 + j * 16 + lo;
        const float bv = bias[col];
#pragma unroll
        for (int r = 0; r < 4; r++)
          C[(size_t)(row + r) * D_ + col] = (__bf16)(acc[i][j][r] + bv);
      }
    }
  }
}

// ---------------------------------------------------------------------------
// Sliding-window attention v7 (unchanged from R11): 4-buffer K/V, 2 tiles
// per barrier epoch (3 barriers/block), f-sequential per-wave P slab,
// streaming softmax without max subtraction. 73728 B LDS -> 2 blocks/CU.
__global__ __launch_bounds__(256, 2) void attn_win7(
    const __bf16* __restrict__ Qp, const __bf16* __restrict__ Kp,
    const __bf16* __restrict__ Vt, __bf16* __restrict__ ctx) {
  __shared__ __bf16 smem[36864];  // 73728 B
  const int qt = blockIdx.x, h = blockIdx.y, b = blockIdx.z;
  const int q0 = qt * 128;
  const int tid = threadIdx.x, wave = tid >> 6, lane = tid & 63;
  const int lo = lane & 15, quad = lane >> 4;
  const int tmin = (q0 >= 256) ? 0 : ((256 - q0) >> 6);  // 0, 2, or 4
  const __bf16* Kg = Kp + (size_t)b * S_ * D_ + h * DH_;
  const __bf16* Vg = Vt + (size_t)(b * H_ + h) * DH_ * S_;
  const size_t qbase = ((size_t)b * S_) * D_ + h * DH_;

  const int c0 = tid, c1 = tid + 256;
  const int rA = c0 >> 3, gA = ((c0 & 7) ^ (rA & 7)) * 8;
  const int rB = c1 >> 3, gB = ((c1 & 7) ^ (rB & 7)) * 8;

  auto stageK = [&](int t) {
    const int k0 = q0 - 256 + t * 64;
    const int kb = (t & 3) * 4096;
    gload_lds16(Kg + (size_t)(k0 + rA) * D_ + gA, &smem[kb + c0 * 8]);
    gload_lds16(Kg + (size_t)(k0 + rB) * D_ + gB, &smem[kb + c1 * 8]);
  };
  auto stageV = [&](int t) {
    const int k0 = q0 - 256 + t * 64;
    const int vb = 16384 + (t & 3) * 4096;
    gload_lds16(Vg + (size_t)rA * S_ + k0 + gA, &smem[vb + c0 * 8]);
    gload_lds16(Vg + (size_t)rB * S_ + k0 + gB, &smem[vb + c1 * 8]);
  };
  auto stagePair = [&](int p) {  // tiles 2p, 2p+1
    stageK(2 * p); stageV(2 * p);
    stageK(2 * p + 1); stageV(2 * p + 1);
  };

  bf16x8 qf[2][2];
#pragma unroll
  for (int f = 0; f < 2; f++) {
    const int qr = q0 + wave * 32 + f * 16 + lo;
    qf[f][0] = *(const bf16x8*)&Qp[qbase + (size_t)qr * D_ + quad * 8];
    qf[f][1] = *(const bf16x8*)&Qp[qbase + (size_t)qr * D_ + 32 + quad * 8];
  }

  const int p0 = tmin >> 1;
  stagePair(p0);
  if (p0 + 1 <= 2) stagePair(p0 + 1);
  __syncthreads();

  const int g0 = (quad ^ (lo & 7)) * 8;
  const int g1 = ((quad + 4) ^ (lo & 7)) * 8;

  const int pwb = 32768 + wave * 1024;  // 16 rows x 64, XOR seg swizzle
  float rs[2][4] = {};
  f32x4 oacc[2][4] = {};

#pragma unroll
  for (int p = 0; p < 3; p++) {
    if (p < p0) continue;
#pragma unroll
    for (int u = 0; u < 2; u++) {
      const int t = 2 * p + u;
      const int kb = (t & 3) * 4096, vb = 16384 + (t & 3) * 4096;
      const int kmin = t * 64 - 256;
      const bool active =
          (kmin <= wave * 32 + 31) && (kmin + 63 > wave * 32 - 256);
      if (active) {
        f32x4 sc[2][4];
#pragma unroll
        for (int kt = 0; kt < 4; kt++) {
          const int kr = kt * 16 + lo;
          const bf16x8 kf0 = *(const bf16x8*)&smem[kb + kr * 64 + g0];
          const bf16x8 kf1 = *(const bf16x8*)&smem[kb + kr * 64 + g1];
#pragma unroll
          for (int f = 0; f < 2; f++) {
            f32x4 c = {0.f, 0.f, 0.f, 0.f};
            c = MFMA16(qf[f][0], kf0, c);
            c = MFMA16(qf[f][1], kf1, c);
            sc[f][kt] = c;
          }
        }
#pragma unroll
        for (int f = 0; f < 2; f++)
#pragma unroll
          for (int kt = 0; kt < 4; kt++)
#pragma unroll
            for (int r = 0; r < 4; r++) {
              const int delta =
                  kmin + kt * 16 + lo - (wave * 32 + f * 16 + quad * 4 + r);
              const bool keep = (delta <= 0) && (delta > -256);
              const float e = __expf(fmaf(sc[f][kt][r], 0.125f, -8.0f));
              const float pv = keep ? e : 0.0f;
              sc[f][kt][r] = pv;
              rs[f][r] += pv;
            }
        bf16x8 pf[2][2];
#pragma unroll
        for (int f = 0; f < 2; f++) {
#pragma unroll
          for (int kt = 0; kt < 4; kt++)
#pragma unroll
            for (int r = 0; r < 4; r++) {
              const int row = quad * 4 + r;
              const int col = kt * 16 + lo;
              smem[pwb + row * 64 + (((col >> 3) ^ (row & 7)) * 8) + (col & 7)] =
                  (__bf16)sc[f][kt][r];
            }
          pf[f][0] = *(const bf16x8*)&smem[pwb + lo * 64 + g0];
          pf[f][1] = *(const bf16x8*)&smem[pwb + lo * 64 + g1];
        }
#pragma unroll
        for (int ds = 0; ds < 4; ds++) {
          const bf16x8 vf0 = *(const bf16x8*)&smem[vb + (ds * 16 + lo) * 64 + g0];
          const bf16x8 vf1 = *(const bf16x8*)&smem[vb + (ds * 16 + lo) * 64 + g1];
#pragma unroll
          for (int f = 0; f < 2; f++) {
            oacc[f][ds] = MFMA16(pf[f][0], vf0, oacc[f][ds]);
            oacc[f][ds] = MFMA16(pf[f][1], vf1, oacc[f][ds]);
          }
        }
      }
    }
    if (p < 2) {
      __syncthreads();                   // all waves done with buffers (p pair)
      if (p + 2 <= 2) stagePair(p + 2);  // refill; ~2 tiles of compute cover
    }
  }

#pragma unroll
  for (int f = 0; f < 2; f++)
#pragma unroll
    for (int r = 0; r < 4; r++)
#pragma unroll
      for (int off = 1; off < 16; off <<= 1)
        rs[f][r] += __shfl_xor(rs[f][r], off);

#pragma unroll
  for (int f = 0; f < 2; f++)
#pragma unroll
    for (int ds = 0; ds < 4; ds++)
#pragma unroll
      for (int r = 0; r < 4; r++) {
        const int qg = q0 + wave * 32 + f * 16 + quad * 4 + r;
        ctx[((size_t)b * S_ + qg) * D_ + h * DH_ + ds * 16 + lo] =
            (__bf16)(oacc[f][ds][r] / rs[f][r]);
      }
}

// ---------------------------------------------------------------------------
// Output projection, BK=128: 8 K-iterations (half the barrier events of
// BK=64), 48 KB LDS -- still 2 blocks/CU (96 KB < 160), so unlike the
// m132 case this halves drains at no occupancy cost. 16-seg XOR swizzle
// keeps fragment ds_read_b128 at free 2-way conflicts.
__global__ __launch_bounds__(256, 2) void gemm_o(
    const __bf16* __restrict__ A, const __bf16* __restrict__ W,
    const float* __restrict__ bias, float* __restrict__ C) {
  __shared__ __bf16 As[64 * 128];    // 16 KB
  __shared__ __bf16 Bs[128 * 128];   // 32 KB
  const int tid = threadIdx.x, lane = tid & 63, wave = tid >> 6;
  const int lo = lane & 15, quad = lane >> 4;
  const int wr = wave & 1, wc = wave >> 1;
  const int bn = blockIdx.x, bm = blockIdx.y;
  const __bf16* Ag = A + (size_t)bn * 64 * D_;
  const __bf16* Wg = W + (size_t)bm * 128 * D_;
  // chunks: row = c>>4, phys seg c&15 holds global seg (c&15)^(row&7)
  int arow[4], aoff[4], brow[8], boff[8];
#pragma unroll
  for (int u = 0; u < 4; u++) {
    const int c = tid + u * 256;
    arow[u] = c >> 4; aoff[u] = (((c & 15) ^ ((c >> 4) & 7)) * 8);
  }
#pragma unroll
  for (int u = 0; u < 8; u++) {
    const int c = tid + u * 256;
    brow[u] = c >> 4; boff[u] = (((c & 15) ^ ((c >> 4) & 7)) * 8);
  }
  f32x4 acc[2][4] = {};
  for (int k0 = 0; k0 < D_; k0 += 128) {
    __syncthreads();
#pragma unroll
    for (int u = 0; u < 4; u++)
      gload_lds16(Ag + (size_t)arow[u] * D_ + k0 + aoff[u], &As[(tid + u * 256) * 8]);
#pragma unroll
    for (int u = 0; u < 8; u++)
      gload_lds16(Wg + (size_t)brow[u] * D_ + k0 + boff[u], &Bs[(tid + u * 256) * 8]);
    __syncthreads();
#pragma unroll
    for (int h = 0; h < 4; h++) {
      bf16x8 af[2], bfr[4];
#pragma unroll
      for (int i = 0; i < 2; i++) {
        const int r = wr * 32 + i * 16 + lo;
        af[i] = *(const bf16x8*)&As[r * 128 + (((h * 4 + quad) ^ (r & 7)) * 8)];
      }
#pragma unroll
      for (int j = 0; j < 4; j++) {
        const int r = wc * 64 + j * 16 + lo;
        bfr[j] = *(const bf16x8*)&Bs[r * 128 + (((h * 4 + quad) ^ (r & 7)) * 8)];
      }
#pragma unroll
      for (int i = 0; i < 2; i++)
#pragma unroll
        for (int j = 0; j < 4; j++)
          acc[i][j] = MFMA16(af[i], bfr[j], acc[i][j]);
    }
  }
#pragma unroll
  for (int i = 0; i < 2; i++) {
    const int row = bn * 64 + wr * 32 + i * 16 + quad * 4;
#pragma unroll
    for (int j = 0; j < 4; j++) {
      const int col = bm * 128 + wc * 64 + j * 16 + lo;
      const float bv = bias[col];
#pragma unroll
      for (int r = 0; r < 4; r++)
        C[(size_t)(row + r) * D_ + col] = acc[i][j][r] + bv;
    }
  }
}

// ---------------------------------------------------------------------------
extern "C" void kernel_launch(void* const* d_in, const int* in_sizes, int n_in,
                              void* d_out, int out_size, void* d_ws, size_t ws_size,
                              hipStream_t stream) {
  (void)in_sizes; (void)n_in; (void)out_size; (void)ws_size;
  const float* q_in = (const float*)d_in[0];
  const float* k_in = (const float*)d_in[1];
  const float* v_in = (const float*)d_in[2];
  const float* Wq   = (const float*)d_in[3];
  const float* bq   = (const float*)d_in[4];
  const float* Wk   = (const float*)d_in[5];
  const float* bk   = (const float*)d_in[6];
  const float* Wv   = (const float*)d_in[7];
  const float* bv   = (const float*)d_in[8];
  const float* Wo   = (const float*)d_in[9];
  const float* bo   = (const float*)d_in[10];

  const size_t XN = (size_t)NROW * D_;  // 4M elems
  const size_t WN = (size_t)D_ * D_;    // 1M elems
  char* ws = (char*)d_ws;               // 64 MB total
  __bf16* xq  = (__bf16*)ws; ws += XN * 2;
  __bf16* xk  = (__bf16*)ws; ws += XN * 2;
  __bf16* xv  = (__bf16*)ws; ws += XN * 2;
  __bf16* wqb = (__bf16*)ws; ws += WN * 2;
  __bf16* wkb = (__bf16*)ws; ws += WN * 2;
  __bf16* wvb = (__bf16*)ws; ws += WN * 2;
  __bf16* wob = (__bf16*)ws; ws += WN * 2;
  __bf16* Qp  = (__bf16*)ws; ws += XN * 2;
  __bf16* Kp  = (__bf16*)ws; ws += XN * 2;
  __bf16* Vtp = (__bf16*)ws; ws += XN * 2;  // [B][H][DH][S]
  __bf16* ctx = (__bf16*)ws; ws += XN * 2;

  CastArgs ca;
  ca.src[0] = q_in; ca.src[1] = k_in; ca.src[2] = v_in;
  ca.src[3] = Wq; ca.src[4] = Wk; ca.src[5] = Wv; ca.src[6] = Wo;
  ca.dst[0] = xq; ca.dst[1] = xk; ca.dst[2] = xv;
  ca.dst[3] = wqb; ca.dst[4] = wkb; ca.dst[5] = wvb; ca.dst[6] = wob;
  cast_all<<<16384, 256, 0, stream>>>(ca);

  QKVArgs qa;
  qa.A[0] = xq;  qa.A[1] = xk;  qa.A[2] = xv;
  qa.W[0] = wqb; qa.W[1] = wkb; qa.W[2] = wvb;
  qa.bias[0] = bq; qa.bias[1] = bk; qa.bias[2] = bv;
  qa.C[0] = Qp; qa.C[1] = Kp; qa.C[2] = Vtp;
  gemm_qkv<<<dim3(NROW / 128, D_ / 128, 3), 256, 0, stream>>>(qa);

  attn_win7<<<dim3(S_ / 128, H_, B_), 256, 0, stream>>>(Qp, Kp, Vtp, ctx);

  gemm_o<<<dim3(NROW / 64, D_ / 128), 256, 0, stream>>>(ctx, wob, bo, (float*)d_out);
}